// Round 2
// baseline (1073.133 us; speedup 1.0000x reference)
//
#include <hip/hip_runtime.h>

#define B_ 2
#define T_ 8
#define Z_ 20
#define Y_ 64
#define X_ 64
#define C_ 2
#define F1_ 32
#define F_ 32

constexpr int NPTS = B_*T_*Z_*Y_*X_;   // 1,310,720
constexpr int ZYX  = Z_*Y_*X_;         // 81,920
constexpr int NTILES = NPTS / 16;      // 81,920
constexpr int TEMPORAL_BLOCKS = 1280;  // 5120 waves, 16 tiles each

using bf8   = __attribute__((ext_vector_type(8))) short;
using f32x4 = __attribute__((ext_vector_type(4))) float;
using u16x8 = __attribute__((ext_vector_type(8))) unsigned short;

__device__ inline unsigned short f2bf(float x) {   // RNE float->bf16
    unsigned u = __builtin_bit_cast(unsigned, x);
    return (unsigned short)((u + 0x7fff + ((u >> 16) & 1)) >> 16);
}

// ---------------------------------------------------------------------------
// Weight projection.
// blocks 0..31: spatial filter f (zero-mean + norm), output packed as
//   w4[(tap*32+f)*4 + {0:w0r, 1:w1r, 2:w0i, 3:w1i}]  (tap = 27 kz,ky,kx taps)
// blocks 32..63: temporal filter f (norm only), plain [kt][f1][f] layout.
// ---------------------------------------------------------------------------
__global__ __launch_bounds__(64) void project_kernel(
    const float* __restrict__ wxr, const float* __restrict__ wxi,
    const float* __restrict__ wtr, const float* __restrict__ wti,
    float* __restrict__ w4,
    float* __restrict__ otr, float* __restrict__ oti)
{
    const int bid  = blockIdx.x;
    const int lane = threadIdx.x;

    if (bid < F1_) {
        const int f = bid;
        float er = 0.f, ei = 0.f;
        if (lane < 54) { er = wxr[lane*F1_ + f]; ei = wxi[lane*F1_ + f]; }
        float sr = er, si = ei;
        #pragma unroll
        for (int o = 32; o >= 1; o >>= 1) { sr += __shfl_xor(sr, o); si += __shfl_xor(si, o); }
        const float mr = sr * (1.f/54.f), mi = si * (1.f/54.f);
        const float dr = er - mr, di = ei - mi;
        float sq = (lane < 54) ? (dr*dr + di*di) : 0.f;
        #pragma unroll
        for (int o = 32; o >= 1; o >>= 1) sq += __shfl_xor(sq, o);
        const float s = 1.f / fmaxf(sqrtf(sq), 1.f);
        if (lane < 54) {
            const int tap = lane >> 1, cin = lane & 1;
            w4[(tap*F1_ + f)*4 + cin]     = dr*s;
            w4[(tap*F1_ + f)*4 + 2 + cin] = di*s;
        }
    } else {
        const int f = bid - F1_;
        float er[2], ei[2];
        float sq = 0.f;
        #pragma unroll
        for (int k = 0; k < 2; ++k) {
            const int e = lane + k*64;   // 0..95 valid
            if (e < 96) { er[k] = wtr[e*F_ + f]; ei[k] = wti[e*F_ + f]; sq += er[k]*er[k] + ei[k]*ei[k]; }
            else        { er[k] = 0.f;  ei[k] = 0.f; }
        }
        #pragma unroll
        for (int o = 32; o >= 1; o >>= 1) sq += __shfl_xor(sq, o);
        const float s = 1.f / fmaxf(sqrtf(sq), 1.f);
        #pragma unroll
        for (int k = 0; k < 2; ++k) {
            const int e = lane + k*64;
            if (e < 96) { otr[e*F_ + f] = er[k]*s; oti[e*F_ + f] = ei[k]*s; }
        }
    }
}

// ---------------------------------------------------------------------------
// Pack temporal weights into MFMA B-fragment order, complex folded into real:
// K = 192: k = (kt*32+f1)*2 + c (c: 0=r,1=i).  N = 64: n<32 -> yr[f], n>=32 -> yi[f].
// W[k][n<32] = c? -wi : wr ;  W[k][n>=32] = c? wr : wi.
// Fragment order: wp[((ct*6+kb)*64 + lane)*8 + j] = W[kb*32+(lane>>4)*8+j][ct*16+(lane&15)]
// ---------------------------------------------------------------------------
__global__ __launch_bounds__(256) void pack_wt_kernel(
    const float* __restrict__ ptr_, const float* __restrict__ pti,
    unsigned short* __restrict__ wp)
{
    for (int o = threadIdx.x; o < 4*6*64*8; o += 256) {
        const int j  = o & 7;
        const int l  = (o >> 3) & 63;
        const int g  = o >> 9;          // ct*6 + kb
        const int kb = g % 6, ct = g / 6;
        const int k  = kb*32 + (l >> 4)*8 + j;
        const int n  = ct*16 + (l & 15);
        const int kt = k >> 6, f1 = (k >> 1) & 31, c = k & 1;
        const int f  = n & 31;
        const float wr = ptr_[(kt*F1_ + f1)*F_ + f];
        const float wi = pti[(kt*F1_ + f1)*F_ + f];
        const float v  = (n < 32) ? (c ? -wi : wr) : (c ? wr : wi);
        wp[o] = f2bf(v);
    }
}

// ---------------------------------------------------------------------------
// Spatial 3x3x3 complex conv, symmetric pad. Thread = one point, 32 complex
// outputs in regs, float4 weight reads from LDS. Emits bf16 interleaved sp:
// sp[p*64 + f1*2 + c]  (c: 0=r, 1=i)  -- this is the MFMA A-operand layout.
// ---------------------------------------------------------------------------
__global__ __launch_bounds__(256) void spatial_kernel(
    const float* __restrict__ xr, const float* __restrict__ xi,
    const float* __restrict__ w4,
    unsigned short* __restrict__ sp)
{
    __shared__ float4 s_w[27*F1_];
    for (int i = threadIdx.x; i < 27*F1_; i += 256)
        s_w[i] = reinterpret_cast<const float4*>(w4)[i];
    __syncthreads();

    const int p   = blockIdx.x * 256 + threadIdx.x;
    const int x   = p & 63;
    const int y   = (p >> 6) & 63;
    const int zbt = p >> 12;
    const int z   = zbt % Z_;
    const int bt  = zbt / Z_;
    const int btbase = bt * ZYX;

    float accr[F1_], acci[F1_];
    #pragma unroll
    for (int f = 0; f < F1_; ++f) { accr[f] = 0.f; acci[f] = 0.f; }

    #pragma unroll 1
    for (int kz = 0; kz < 3; ++kz) {
        int zz = z + kz - 1; zz = zz < 0 ? -zz-1 : (zz >= Z_ ? 2*Z_-1-zz : zz);
        #pragma unroll 1
        for (int ky = 0; ky < 3; ++ky) {
            int yy = y + ky - 1; yy = yy < 0 ? -yy-1 : (yy >= Y_ ? 2*Y_-1-yy : yy);
            #pragma unroll
            for (int kx = 0; kx < 3; ++kx) {
                int xx = x + kx - 1; xx = xx < 0 ? -xx-1 : (xx >= X_ ? 2*X_-1-xx : xx);
                const int ip = (btbase + zz*(Y_*X_) + yy*X_ + xx) * C_;
                const float2 vr = *reinterpret_cast<const float2*>(xr + ip);
                const float2 vi = *reinterpret_cast<const float2*>(xi + ip);
                const float4* wrow = &s_w[((kz*3 + ky)*3 + kx) * F1_];
                #pragma unroll
                for (int f = 0; f < F1_; ++f) {
                    const float4 w = wrow[f];
                    accr[f] += vr.x*w.x + vr.y*w.y - vi.x*w.z - vi.y*w.w;
                    acci[f] += vr.x*w.z + vr.y*w.w + vi.x*w.x + vi.y*w.y;
                }
            }
        }
    }

    unsigned short* op = sp + (size_t)p * 64;
    #pragma unroll
    for (int f0 = 0; f0 < F1_; f0 += 4) {
        u16x8 v;
        #pragma unroll
        for (int j = 0; j < 4; ++j) {
            v[2*j]   = f2bf(accr[f0+j]);
            v[2*j+1] = f2bf(acci[f0+j]);
        }
        *reinterpret_cast<u16x8*>(op + f0*2) = v;
    }
}

// ---------------------------------------------------------------------------
// Temporal conv as MFMA GEMM: [NPTS x 192] x [192 x 64].
// Wave = 16-point tile; B (weights) held in 96 VGPRs, loaded once.
// A-frag: lane holds sp[p0 + (lane&15)] elems k = kb*32 + (lane>>4)*8 + j.
// 24 MFMAs (6 kb x 4 col-tiles) per tile.
// ---------------------------------------------------------------------------
__global__ __launch_bounds__(256) void temporal_mfma_kernel(
    const unsigned short* __restrict__ sp,
    const unsigned short* __restrict__ wp,
    float* __restrict__ yr, float* __restrict__ yi)
{
    const int lane = threadIdx.x & 63;
    const int wid  = threadIdx.x >> 6;
    const int gw   = blockIdx.x * 4 + wid;

    // B fragments: 24 x 16B per lane (96 VGPRs), same for all waves (L2 hit)
    bf8 bfrag[4][6];
    const bf8* wp8 = reinterpret_cast<const bf8*>(wp);
    #pragma unroll
    for (int ct = 0; ct < 4; ++ct)
        #pragma unroll
        for (int kb = 0; kb < 6; ++kb)
            bfrag[ct][kb] = wp8[(ct*6 + kb)*64 + lane];

    const int row = lane & 15;
    const int kch = lane >> 4;

    for (int tile = gw; tile < NTILES; tile += TEMPORAL_BLOCKS*4) {
        const int p0   = tile * 16;
        const int bt   = p0 / ZYX;            // uniform within tile (ZYX%16==0)
        const int zyx  = (p0 - bt*ZYX) + row;
        const int t    = bt % T_;
        const int b    = bt / T_;

        bf8 afrag[6];
        #pragma unroll
        for (int kt = 0; kt < 3; ++kt) {
            int tt = t + kt - 1; tt = tt < 0 ? 0 : (tt >= T_ ? T_-1 : tt);
            const unsigned short* base = sp + ((size_t)(b*T_ + tt)*ZYX + zyx)*64;
            afrag[kt*2+0] = *reinterpret_cast<const bf8*>(base + kch*8);
            afrag[kt*2+1] = *reinterpret_cast<const bf8*>(base + 32 + kch*8);
        }

        f32x4 acc[4];
        #pragma unroll
        for (int ct = 0; ct < 4; ++ct) acc[ct] = (f32x4){0.f, 0.f, 0.f, 0.f};

        #pragma unroll
        for (int ct = 0; ct < 4; ++ct)
            #pragma unroll
            for (int kb = 0; kb < 6; ++kb)
                acc[ct] = __builtin_amdgcn_mfma_f32_16x16x32_bf16(
                              afrag[kb], bfrag[ct][kb], acc[ct], 0, 0, 0);

        // C/D: col = lane&15, point-row = p0 + (lane>>4)*4 + j
        const int prow0 = p0 + (lane >> 4)*4;
        #pragma unroll
        for (int ct = 0; ct < 4; ++ct) {
            float* outp = (ct < 2) ? yr : yi;
            const int f = (ct & 1)*16 + (lane & 15);
            #pragma unroll
            for (int j = 0; j < 4; ++j)
                outp[(size_t)(prow0 + j)*F_ + f] = acc[ct][j];
        }
    }
}

extern "C" void kernel_launch(void* const* d_in, const int* in_sizes, int n_in,
                              void* d_out, int out_size, void* d_ws, size_t ws_size,
                              hipStream_t stream)
{
    const float* xr  = (const float*)d_in[0];
    const float* xi  = (const float*)d_in[1];
    const float* wxr = (const float*)d_in[2];
    const float* wxi = (const float*)d_in[3];
    const float* wtr = (const float*)d_in[4];
    const float* wti = (const float*)d_in[5];

    float* ws   = (float*)d_ws;
    float* w4   = ws;                                   // 3456 floats
    float* ptr_ = ws + 4096;                            // 3072
    float* pti  = ws + 8192;                            // 3072
    unsigned short* wp = (unsigned short*)(ws + 12288); // 12288 ushorts (24KB)
    unsigned short* sp = (unsigned short*)(ws + 32768); // NPTS*64 bf16 (168MB)

    float* yr = (float*)d_out;
    float* yi = yr + (size_t)NPTS * F_;

    hipLaunchKernelGGL(project_kernel, dim3(64), dim3(64), 0, stream,
                       wxr, wxi, wtr, wti, w4, ptr_, pti);
    hipLaunchKernelGGL(pack_wt_kernel, dim3(1), dim3(256), 0, stream,
                       ptr_, pti, wp);
    hipLaunchKernelGGL(spatial_kernel, dim3(NPTS/256), dim3(256), 0, stream,
                       xr, xi, w4, sp);
    hipLaunchKernelGGL(temporal_mfma_kernel, dim3(TEMPORAL_BLOCKS), dim3(256), 0, stream,
                       sp, wp, yr, yi);
}

// Round 3
// 241.492 us; speedup vs baseline: 4.4438x; 4.4438x over previous
//
#include <hip/hip_runtime.h>

#define B_ 2
#define T_ 8
#define Z_ 20
#define Y_ 64
#define X_ 64
#define C_ 2
#define F1_ 32
#define F_ 32

constexpr int NPTS = B_*T_*Z_*Y_*X_;   // 1,310,720
constexpr int ZYX  = Z_*Y_*X_;         // 81,920
constexpr int NTILES = NPTS / 16;      // 81,920
constexpr int TEMPORAL_BLOCKS = 1280;  // 5120 waves, 16 tiles each

using bf8   = __attribute__((ext_vector_type(8))) short;
using f32x4 = __attribute__((ext_vector_type(4))) float;

__device__ inline unsigned short f2bf(float x) {   // RNE float->bf16
    unsigned u = __builtin_bit_cast(unsigned, x);
    return (unsigned short)((u + 0x7fff + ((u >> 16) & 1)) >> 16);
}

// ---------------------------------------------------------------------------
// Weight projection. blocks 0..31: spatial filter f (zero-mean + norm),
// plain layout psr/psi[(tap*2+cin)*32 + f]. blocks 32..63: temporal filter f
// (norm only), plain [kt][f1][f].
// ---------------------------------------------------------------------------
__global__ __launch_bounds__(64) void project_kernel(
    const float* __restrict__ wxr, const float* __restrict__ wxi,
    const float* __restrict__ wtr, const float* __restrict__ wti,
    float* __restrict__ psr, float* __restrict__ psi,
    float* __restrict__ otr, float* __restrict__ oti)
{
    const int bid  = blockIdx.x;
    const int lane = threadIdx.x;

    if (bid < F1_) {
        const int f = bid;
        float er = 0.f, ei = 0.f;
        if (lane < 54) { er = wxr[lane*F1_ + f]; ei = wxi[lane*F1_ + f]; }
        float sr = er, si = ei;
        #pragma unroll
        for (int o = 32; o >= 1; o >>= 1) { sr += __shfl_xor(sr, o); si += __shfl_xor(si, o); }
        const float mr = sr * (1.f/54.f), mi = si * (1.f/54.f);
        const float dr = er - mr, di = ei - mi;
        float sq = (lane < 54) ? (dr*dr + di*di) : 0.f;
        #pragma unroll
        for (int o = 32; o >= 1; o >>= 1) sq += __shfl_xor(sq, o);
        const float s = 1.f / fmaxf(sqrtf(sq), 1.f);
        if (lane < 54) { psr[lane*F1_ + f] = dr*s; psi[lane*F1_ + f] = di*s; }
    } else {
        const int f = bid - F1_;
        float er[2], ei[2];
        float sq = 0.f;
        #pragma unroll
        for (int k = 0; k < 2; ++k) {
            const int e = lane + k*64;   // 0..95 valid
            if (e < 96) { er[k] = wtr[e*F_ + f]; ei[k] = wti[e*F_ + f]; sq += er[k]*er[k] + ei[k]*ei[k]; }
            else        { er[k] = 0.f;  ei[k] = 0.f; }
        }
        #pragma unroll
        for (int o = 32; o >= 1; o >>= 1) sq += __shfl_xor(sq, o);
        const float s = 1.f / fmaxf(sqrtf(sq), 1.f);
        #pragma unroll
        for (int k = 0; k < 2; ++k) {
            const int e = lane + k*64;
            if (e < 96) { otr[e*F_ + f] = er[k]*s; oti[e*F_ + f] = ei[k]*s; }
        }
    }
}

// ---------------------------------------------------------------------------
// Pack both weight sets into MFMA B-fragment order (bf16).
// Spatial: K=128 (k = tap*4 + q, q=(cp*2+cin), zero for k>=108), N=64
//   (n<32: real-out f1=n, n>=32: imag-out f1=n-32).
//   wsp[((ct*4+kb)*64 + l)*8 + j] = W[kb*32+(l>>4)*8+j][ct*16+(l&15)]
// Temporal: K=192 (k=(kt*32+f1)*2+c), N=64.
//   wp[((ct*6+kb)*64 + l)*8 + j] = W[kb*32+(l>>4)*8+j][ct*16+(l&15)]
// ---------------------------------------------------------------------------
__global__ __launch_bounds__(256) void pack_kernel(
    const float* __restrict__ psr, const float* __restrict__ psi,
    const float* __restrict__ ptr_, const float* __restrict__ pti,
    unsigned short* __restrict__ wsp, unsigned short* __restrict__ wp)
{
    for (int o = threadIdx.x; o < 16*64*8; o += 256) {
        const int j  = o & 7;
        const int l  = (o >> 3) & 63;
        const int g  = o >> 9;
        const int kb = g & 3, ct = g >> 2;
        const int k  = kb*32 + (l >> 4)*8 + j;
        const int n  = ct*16 + (l & 15);
        float v = 0.f;
        if (k < 108) {
            const int tap = k >> 2, q = k & 3, cin = q & 1, cp = q >> 1;
            const int f  = n & 31;
            const float wr = psr[(tap*2 + cin)*F1_ + f];
            const float wi = psi[(tap*2 + cin)*F1_ + f];
            v = (n < 32) ? (cp ? -wi : wr) : (cp ? wr : wi);
        }
        wsp[o] = f2bf(v);
    }
    for (int o = threadIdx.x; o < 4*6*64*8; o += 256) {
        const int j  = o & 7;
        const int l  = (o >> 3) & 63;
        const int g  = o >> 9;          // ct*6 + kb
        const int kb = g % 6, ct = g / 6;
        const int k  = kb*32 + (l >> 4)*8 + j;
        const int n  = ct*16 + (l & 15);
        const int kt = k >> 6, f1 = (k >> 1) & 31, c = k & 1;
        const int f  = n & 31;
        const float wr = ptr_[(kt*F1_ + f1)*F_ + f];
        const float wi = pti[(kt*F1_ + f1)*F_ + f];
        const float v  = (n < 32) ? (c ? -wi : wr) : (c ? wr : wi);
        wp[o] = f2bf(v);
    }
}

// ---------------------------------------------------------------------------
// Spatial 3x3x3 complex conv as MFMA GEMM with im2col staged in LDS.
// Block = (bt, z, 4 y-rows). LDS tile: [3 z][6 y][66 x] x (r0,r1,i0,i1) bf16.
// Wave = one y-row; loops 4 x-tiles of 16 points; 16 MFMAs per tile.
// Emits bf16 interleaved sp[p*64 + f1*2 + c].
// ---------------------------------------------------------------------------
__global__ __launch_bounds__(256, 3) void spatial_mfma_kernel(
    const float* __restrict__ xr, const float* __restrict__ xi,
    const unsigned short* __restrict__ wsp,
    unsigned short* __restrict__ sp)
{
    __shared__ uint2 xs[3*6*66];

    const int tid  = threadIdx.x;
    const int lane = tid & 63;
    const int wid  = tid >> 6;

    const int bq = blockIdx.x;
    const int yq = bq & 15;              // Y/4 = 16
    const int z  = (bq >> 4) % Z_;
    const int bt = bq / (16*Z_);
    const int y0 = yq * 4;

    // ---- stage input halo tile (reflect pad=1 applied here) ----
    for (int it = tid; it < 3*6*66; it += 256) {
        const int iz  = it / 396;
        const int rem = it - iz*396;
        const int iy  = rem / 66;
        const int ix  = rem - iy*66;
        int zz = z  + iz - 1; zz = zz < 0 ? 0 : (zz >= Z_ ? Z_-1 : zz);
        int yy = y0 + iy - 1; yy = yy < 0 ? 0 : (yy >= Y_ ? Y_-1 : yy);
        int xx = ix - 1;      xx = xx < 0 ? 0 : (xx >= X_ ? X_-1 : xx);
        const size_t ip = ((size_t)((bt*Z_ + zz)*Y_ + yy)*X_ + xx)*2;
        const float2 vr = *reinterpret_cast<const float2*>(xr + ip);
        const float2 vi = *reinterpret_cast<const float2*>(xi + ip);
        uint2 v;
        v.x = (unsigned)f2bf(vr.x) | ((unsigned)f2bf(vr.y) << 16);
        v.y = (unsigned)f2bf(vi.x) | ((unsigned)f2bf(vi.y) << 16);
        xs[it] = v;
    }

    // ---- B fragments: 16 x 16B per lane (64 VGPRs), broadcast from L2 ----
    bf8 bfrag[4][4];   // [ct][kb]
    const bf8* w8 = reinterpret_cast<const bf8*>(wsp);
    #pragma unroll
    for (int ct = 0; ct < 4; ++ct)
        #pragma unroll
        for (int kb = 0; kb < 4; ++kb)
            bfrag[ct][kb] = w8[(ct*4 + kb)*64 + lane];

    // ---- per-lane A-gather offsets (uint2 index) for 4 kb x 2 taps ----
    const int wy = wid;
    const int lx = lane & 15;
    const int lg = lane >> 4;
    int offi[4][2];
    #pragma unroll
    for (int kb = 0; kb < 4; ++kb)
        #pragma unroll
        for (int s = 0; s < 2; ++s) {
            int ta = kb*8 + lg*2 + s; if (ta > 26) ta = 26;   // k>=108 has B=0
            const int dz = ta/9, dyx = ta - dz*9, dy = dyx/3, dx = dyx - dy*3;
            offi[kb][s] = (dz*6 + wy + dy)*66 + lx + dx;
        }

    __syncthreads();

    const size_t p_row = ((size_t)(bt*Z_ + z)*Y_ + (y0 + wy))*(size_t)X_;
    unsigned* sp32 = reinterpret_cast<unsigned*>(sp);

    #pragma unroll 1
    for (int x0 = 0; x0 < X_; x0 += 16) {
        bf8 af[4];
        #pragma unroll
        for (int kb = 0; kb < 4; ++kb) {
            const uint2 lo = xs[offi[kb][0] + x0];
            const uint2 hi = xs[offi[kb][1] + x0];
            const uint4 comb = make_uint4(lo.x, lo.y, hi.x, hi.y);
            af[kb] = __builtin_bit_cast(bf8, comb);
        }

        f32x4 acc[4];
        #pragma unroll
        for (int ct = 0; ct < 4; ++ct) acc[ct] = (f32x4){0.f, 0.f, 0.f, 0.f};
        #pragma unroll
        for (int ct = 0; ct < 4; ++ct)
            #pragma unroll
            for (int kb = 0; kb < 4; ++kb)
                acc[ct] = __builtin_amdgcn_mfma_f32_16x16x32_bf16(
                              af[kb], bfrag[ct][kb], acc[ct], 0, 0, 0);

        // epilogue: row = x0 + lg*4 + j, cols: ct0/ct2 -> (f1=lx, r/i),
        // ct1/ct3 -> (f1=16+lx, r/i); pack (r,i) bf16 pair into dword
        const int rb = x0 + lg*4;
        #pragma unroll
        for (int j = 0; j < 4; ++j) {
            const size_t p = p_row + rb + j;
            const unsigned v0 = (unsigned)f2bf(acc[0][j]) | ((unsigned)f2bf(acc[2][j]) << 16);
            const unsigned v1 = (unsigned)f2bf(acc[1][j]) | ((unsigned)f2bf(acc[3][j]) << 16);
            sp32[p*32 + lx]      = v0;
            sp32[p*32 + 16 + lx] = v1;
        }
    }
}

// ---------------------------------------------------------------------------
// Temporal conv as MFMA GEMM: [NPTS x 192] x [192 x 64]. Wave = 16-point tile;
// B held in 96 VGPRs. 24 MFMAs per tile.
// ---------------------------------------------------------------------------
__global__ __launch_bounds__(256) void temporal_mfma_kernel(
    const unsigned short* __restrict__ sp,
    const unsigned short* __restrict__ wp,
    float* __restrict__ yr, float* __restrict__ yi)
{
    const int lane = threadIdx.x & 63;
    const int wid  = threadIdx.x >> 6;
    const int gw   = blockIdx.x * 4 + wid;

    bf8 bfrag[4][6];
    const bf8* wp8 = reinterpret_cast<const bf8*>(wp);
    #pragma unroll
    for (int ct = 0; ct < 4; ++ct)
        #pragma unroll
        for (int kb = 0; kb < 6; ++kb)
            bfrag[ct][kb] = wp8[(ct*6 + kb)*64 + lane];

    const int row = lane & 15;
    const int kch = lane >> 4;

    for (int tile = gw; tile < NTILES; tile += TEMPORAL_BLOCKS*4) {
        const int p0   = tile * 16;
        const int bt   = p0 / ZYX;            // uniform within tile (ZYX%16==0)
        const int zyx  = (p0 - bt*ZYX) + row;
        const int t    = bt % T_;
        const int b    = bt / T_;

        bf8 afrag[6];
        #pragma unroll
        for (int kt = 0; kt < 3; ++kt) {
            int tt = t + kt - 1; tt = tt < 0 ? 0 : (tt >= T_ ? T_-1 : tt);
            const unsigned short* base = sp + ((size_t)(b*T_ + tt)*ZYX + zyx)*64;
            afrag[kt*2+0] = *reinterpret_cast<const bf8*>(base + kch*8);
            afrag[kt*2+1] = *reinterpret_cast<const bf8*>(base + 32 + kch*8);
        }

        f32x4 acc[4];
        #pragma unroll
        for (int ct = 0; ct < 4; ++ct) acc[ct] = (f32x4){0.f, 0.f, 0.f, 0.f};

        #pragma unroll
        for (int ct = 0; ct < 4; ++ct)
            #pragma unroll
            for (int kb = 0; kb < 6; ++kb)
                acc[ct] = __builtin_amdgcn_mfma_f32_16x16x32_bf16(
                              afrag[kb], bfrag[ct][kb], acc[ct], 0, 0, 0);

        const int prow0 = p0 + (lane >> 4)*4;
        #pragma unroll
        for (int ct = 0; ct < 4; ++ct) {
            float* outp = (ct < 2) ? yr : yi;
            const int f = (ct & 1)*16 + (lane & 15);
            #pragma unroll
            for (int j = 0; j < 4; ++j)
                outp[(size_t)(prow0 + j)*F_ + f] = acc[ct][j];
        }
    }
}

extern "C" void kernel_launch(void* const* d_in, const int* in_sizes, int n_in,
                              void* d_out, int out_size, void* d_ws, size_t ws_size,
                              hipStream_t stream)
{
    const float* xr  = (const float*)d_in[0];
    const float* xi  = (const float*)d_in[1];
    const float* wxr = (const float*)d_in[2];
    const float* wxi = (const float*)d_in[3];
    const float* wtr = (const float*)d_in[4];
    const float* wti = (const float*)d_in[5];

    float* ws   = (float*)d_ws;
    float* psr  = ws;                                   // 1728
    float* psi  = ws + 2048;                            // 1728
    float* ptr_ = ws + 4096;                            // 3072
    float* pti  = ws + 8192;                            // 3072
    unsigned short* wsp = (unsigned short*)(ws + 12288); // 8192 ushorts (16KB)
    unsigned short* wp  = (unsigned short*)(ws + 16384); // 12288 ushorts (24KB)
    unsigned short* sp  = (unsigned short*)(ws + 32768); // NPTS*64 bf16 (168MB)

    float* yr = (float*)d_out;
    float* yi = yr + (size_t)NPTS * F_;

    hipLaunchKernelGGL(project_kernel, dim3(64), dim3(64), 0, stream,
                       wxr, wxi, wtr, wti, psr, psi, ptr_, pti);
    hipLaunchKernelGGL(pack_kernel, dim3(1), dim3(256), 0, stream,
                       psr, psi, ptr_, pti, wsp, wp);
    hipLaunchKernelGGL(spatial_mfma_kernel, dim3(B_*T_*Z_*(Y_/4)), dim3(256), 0, stream,
                       xr, xi, wsp, sp);
    hipLaunchKernelGGL(temporal_mfma_kernel, dim3(TEMPORAL_BLOCKS), dim3(256), 0, stream,
                       sp, wp, yr, yi);
}

// Round 4
// 101.925 us; speedup vs baseline: 10.5287x; 2.3693x over previous
//
#include <hip/hip_runtime.h>

#define B_ 2
#define T_ 8
#define Z_ 20
#define Y_ 64
#define X_ 64
#define C_ 2
#define F1_ 32
#define F_ 32

constexpr int NPTS = B_*T_*Z_*Y_*X_;   // 1,310,720
constexpr int ZYX  = Z_*Y_*X_;         // 81,920

constexpr int RING_STRIDE = 36;            // dwords/row: 16B-aligned, bank-spread
constexpr int SLOT_DW     = 16*RING_STRIDE;// 576 dwords per ring slot

using bf8   = __attribute__((ext_vector_type(8))) short;
using f32x4 = __attribute__((ext_vector_type(4))) float;

__device__ inline unsigned short f2bf(float x) {   // RNE float->bf16
    unsigned u = __builtin_bit_cast(unsigned, x);
    return (unsigned short)((u + 0x7fff + ((u >> 16) & 1)) >> 16);
}

// ---------------------------------------------------------------------------
// Weight projection (unchanged, verified).
// ---------------------------------------------------------------------------
__global__ __launch_bounds__(64) void project_kernel(
    const float* __restrict__ wxr, const float* __restrict__ wxi,
    const float* __restrict__ wtr, const float* __restrict__ wti,
    float* __restrict__ psr, float* __restrict__ psi,
    float* __restrict__ otr, float* __restrict__ oti)
{
    const int bid  = blockIdx.x;
    const int lane = threadIdx.x;

    if (bid < F1_) {
        const int f = bid;
        float er = 0.f, ei = 0.f;
        if (lane < 54) { er = wxr[lane*F1_ + f]; ei = wxi[lane*F1_ + f]; }
        float sr = er, si = ei;
        #pragma unroll
        for (int o = 32; o >= 1; o >>= 1) { sr += __shfl_xor(sr, o); si += __shfl_xor(si, o); }
        const float mr = sr * (1.f/54.f), mi = si * (1.f/54.f);
        const float dr = er - mr, di = ei - mi;
        float sq = (lane < 54) ? (dr*dr + di*di) : 0.f;
        #pragma unroll
        for (int o = 32; o >= 1; o >>= 1) sq += __shfl_xor(sq, o);
        const float s = 1.f / fmaxf(sqrtf(sq), 1.f);
        if (lane < 54) { psr[lane*F1_ + f] = dr*s; psi[lane*F1_ + f] = di*s; }
    } else {
        const int f = bid - F1_;
        float er[2], ei[2];
        float sq = 0.f;
        #pragma unroll
        for (int k = 0; k < 2; ++k) {
            const int e = lane + k*64;
            if (e < 96) { er[k] = wtr[e*F_ + f]; ei[k] = wti[e*F_ + f]; sq += er[k]*er[k] + ei[k]*ei[k]; }
            else        { er[k] = 0.f;  ei[k] = 0.f; }
        }
        #pragma unroll
        for (int o = 32; o >= 1; o >>= 1) sq += __shfl_xor(sq, o);
        const float s = 1.f / fmaxf(sqrtf(sq), 1.f);
        #pragma unroll
        for (int k = 0; k < 2; ++k) {
            const int e = lane + k*64;
            if (e < 96) { otr[e*F_ + f] = er[k]*s; oti[e*F_ + f] = ei[k]*s; }
        }
    }
}

// ---------------------------------------------------------------------------
// Pack both weight sets into MFMA B-fragment order (bf16). Same math as the
// verified round-3 pack, split across 40 blocks (16 spatial + 24 temporal).
// ---------------------------------------------------------------------------
__global__ __launch_bounds__(256) void pack_kernel(
    const float* __restrict__ psr, const float* __restrict__ psi,
    const float* __restrict__ ptr_, const float* __restrict__ pti,
    unsigned short* __restrict__ wsp, unsigned short* __restrict__ wp)
{
    const int g = blockIdx.x;
    if (g < 16) {
        for (int o = g*512 + threadIdx.x; o < (g+1)*512; o += 256) {
            const int j  = o & 7;
            const int l  = (o >> 3) & 63;
            const int gg = o >> 9;
            const int kb = gg & 3, ct = gg >> 2;
            const int k  = kb*32 + (l >> 4)*8 + j;
            const int n  = ct*16 + (l & 15);
            float v = 0.f;
            if (k < 108) {
                const int tap = k >> 2, q = k & 3, cin = q & 1, cp = q >> 1;
                const int f  = n & 31;
                const float wr = psr[(tap*2 + cin)*F1_ + f];
                const float wi = psi[(tap*2 + cin)*F1_ + f];
                v = (n < 32) ? (cp ? -wi : wr) : (cp ? wr : wi);
            }
            wsp[o] = f2bf(v);
        }
    } else {
        for (int o = (g-16)*512 + threadIdx.x; o < (g-15)*512; o += 256) {
            const int j  = o & 7;
            const int l  = (o >> 3) & 63;
            const int gg = o >> 9;          // ct*6 + kb
            const int kb = gg % 6, ct = gg / 6;
            const int k  = kb*32 + (l >> 4)*8 + j;
            const int n  = ct*16 + (l & 15);
            const int kt = k >> 6, f1 = (k >> 1) & 31, c = k & 1;
            const int f  = n & 31;
            const float wr = ptr_[(kt*F1_ + f1)*F_ + f];
            const float wi = pti[(kt*F1_ + f1)*F_ + f];
            const float v  = (n < 32) ? (c ? -wi : wr) : (c ? wr : wi);
            wp[o] = f2bf(v);
        }
    }
}

// ---------------------------------------------------------------------------
// Repack input to bf16: xb[p] = uint2{ r0|r1<<16, i0|i1<<16 }.
// ---------------------------------------------------------------------------
__global__ __launch_bounds__(256) void repack_kernel(
    const float* __restrict__ xr, const float* __restrict__ xi,
    uint2* __restrict__ xb)
{
    const int p = blockIdx.x*256 + threadIdx.x;
    const float2 vr = *reinterpret_cast<const float2*>(xr + (size_t)p*2);
    const float2 vi = *reinterpret_cast<const float2*>(xi + (size_t)p*2);
    uint2 v;
    v.x = (unsigned)f2bf(vr.x) | ((unsigned)f2bf(vr.y) << 16);
    v.y = (unsigned)f2bf(vi.x) | ((unsigned)f2bf(vi.y) << 16);
    xb[p] = v;
}

// ---------------------------------------------------------------------------
// Fused spatial+temporal kernel. Block = (b,z,y) row; wave = 16-x tile.
// Per t: spatial MFMA (16) -> bf16 slice into wave-private LDS ring (3 slots)
//        -> temporal MFMA (24) emits y(t-1) straight from the ring.
// sp never touches global memory.
// ---------------------------------------------------------------------------
__global__ __launch_bounds__(256) void fused_kernel(
    const uint2* __restrict__ xb,
    const unsigned short* __restrict__ wsp,
    const unsigned short* __restrict__ wp,
    float* __restrict__ yr, float* __restrict__ yi)
{
    __shared__ unsigned ring[4*3*SLOT_DW];   // 27.6 KB

    const int tid  = threadIdx.x;
    const int lane = tid & 63;
    const int wid  = tid >> 6;
    const int lx   = lane & 15;
    const int lg   = lane >> 4;

    const int bq = blockIdx.x;          // b*Z*Y + z*Y + y
    const int y  = bq & 63;
    const int z  = (bq >> 6) % Z_;
    const int b  = bq / (64*Z_);
    const int x0 = wid * 16;

    // ---- B fragments: spatial 16 (64 VGPR) + temporal 24 (96 VGPR) ----
    bf8 wsf[4][4];
    const bf8* w8 = reinterpret_cast<const bf8*>(wsp);
    #pragma unroll
    for (int ct = 0; ct < 4; ++ct)
        #pragma unroll
        for (int kb = 0; kb < 4; ++kb)
            wsf[ct][kb] = w8[(ct*4 + kb)*64 + lane];

    bf8 wtf[4][6];
    const bf8* wp8 = reinterpret_cast<const bf8*>(wp);
    #pragma unroll
    for (int ct = 0; ct < 4; ++ct)
        #pragma unroll
        for (int kb = 0; kb < 6; ++kb)
            wtf[ct][kb] = wp8[(ct*6 + kb)*64 + lane];

    // ---- per-lane input-gather offsets (reflect pad clamps hoisted) ----
    int off[4][2];
    #pragma unroll
    for (int kb = 0; kb < 4; ++kb)
        #pragma unroll
        for (int s = 0; s < 2; ++s) {
            int ta = kb*8 + lg*2 + s; if (ta > 26) ta = 26;   // k>=108: B is 0
            const int dz = ta/9, dyx = ta - dz*9, dy = dyx/3, dx = dyx - dy*3;
            int zz = z + dz - 1;      zz = zz < 0 ? 0 : (zz >= Z_ ? Z_-1 : zz);
            int yy = y + dy - 1;      yy = yy < 0 ? 0 : (yy >= Y_ ? Y_-1 : yy);
            int xx = x0 + lx + dx - 1; xx = xx < 0 ? 0 : (xx >= X_ ? X_-1 : xx);
            off[kb][s] = (zz*Y_ + yy)*X_ + xx;
        }

    unsigned* myring = ring + wid*3*SLOT_DW;
    const size_t yrow_base = (((size_t)b*T_)*Z_ + z)*Y_*X_ + (size_t)y*X_ + x0 + lg*4;

    // emit y(tout) from slices (sa,sb,sc) (already in ring slots slice%3)
    auto EMIT = [&](int sa, int sb, int sc, int tout) {
        const int sl[3] = {sa % 3, sb % 3, sc % 3};
        bf8 af[6];
        #pragma unroll
        for (int kt = 0; kt < 3; ++kt) {
            const unsigned* base = myring + sl[kt]*SLOT_DW + lx*RING_STRIDE + lg*4;
            const uint4 u0 = *reinterpret_cast<const uint4*>(base);
            const uint4 u1 = *reinterpret_cast<const uint4*>(base + 16);
            af[kt*2+0] = __builtin_bit_cast(bf8, u0);
            af[kt*2+1] = __builtin_bit_cast(bf8, u1);
        }
        f32x4 acc[4];
        #pragma unroll
        for (int ct = 0; ct < 4; ++ct) acc[ct] = (f32x4){0.f,0.f,0.f,0.f};
        #pragma unroll
        for (int ct = 0; ct < 4; ++ct)
            #pragma unroll
            for (int kb = 0; kb < 6; ++kb)
                acc[ct] = __builtin_amdgcn_mfma_f32_16x16x32_bf16(
                              af[kb], wtf[ct][kb], acc[ct], 0, 0, 0);
        const size_t prow = yrow_base + (size_t)tout * ZYX;
        #pragma unroll
        for (int ct = 0; ct < 4; ++ct) {
            float* outp = (ct < 2) ? yr : yi;
            const int f = (ct & 1)*16 + lx;
            #pragma unroll
            for (int j = 0; j < 4; ++j)
                outp[(prow + j)*F_ + f] = acc[ct][j];
        }
    };

    #pragma unroll 1
    for (int t = 0; t < T_; ++t) {
        // ---- spatial slice s(t) ----
        const uint2* xt = xb + (size_t)(b*T_ + t)*ZYX;
        bf8 af[4];
        #pragma unroll
        for (int kb = 0; kb < 4; ++kb) {
            const uint2 lo = xt[off[kb][0]];
            const uint2 hi = xt[off[kb][1]];
            af[kb] = __builtin_bit_cast(bf8, make_uint4(lo.x, lo.y, hi.x, hi.y));
        }
        f32x4 acc[4];
        #pragma unroll
        for (int ct = 0; ct < 4; ++ct) acc[ct] = (f32x4){0.f,0.f,0.f,0.f};
        #pragma unroll
        for (int ct = 0; ct < 4; ++ct)
            #pragma unroll
            for (int kb = 0; kb < 4; ++kb)
                acc[ct] = __builtin_amdgcn_mfma_f32_16x16x32_bf16(
                              af[kb], wsf[ct][kb], acc[ct], 0, 0, 0);

        // ---- write slice to ring slot t%3 (bf16, temporal-A layout) ----
        unsigned* slot = myring + (t % 3)*SLOT_DW;
        #pragma unroll
        for (int j = 0; j < 4; ++j) {
            const unsigned v0 = (unsigned)f2bf(acc[0][j]) | ((unsigned)f2bf(acc[2][j]) << 16);
            const unsigned v1 = (unsigned)f2bf(acc[1][j]) | ((unsigned)f2bf(acc[3][j]) << 16);
            unsigned* row = slot + (lg*4 + j)*RING_STRIDE;
            row[lx]      = v0;
            row[16 + lx] = v1;
        }

        // ---- emit y(t-1) = slices (t-2, t-1, t), clamped low ----
        if (t >= 1) EMIT(t-2 < 0 ? 0 : t-2, t-1, t, t-1);
    }
    // ---- tail: y(7) = slices (6,7,7) ----
    EMIT(T_-2, T_-1, T_-1, T_-1);
}

extern "C" void kernel_launch(void* const* d_in, const int* in_sizes, int n_in,
                              void* d_out, int out_size, void* d_ws, size_t ws_size,
                              hipStream_t stream)
{
    const float* xr  = (const float*)d_in[0];
    const float* xi  = (const float*)d_in[1];
    const float* wxr = (const float*)d_in[2];
    const float* wxi = (const float*)d_in[3];
    const float* wtr = (const float*)d_in[4];
    const float* wti = (const float*)d_in[5];

    float* ws   = (float*)d_ws;
    float* psr  = ws;                                    // 1728
    float* psi  = ws + 2048;                             // 1728
    float* ptr_ = ws + 4096;                             // 3072
    float* pti  = ws + 8192;                             // 3072
    unsigned short* wsp = (unsigned short*)(ws + 12288); // 8192 ushorts (16KB)
    unsigned short* wp  = (unsigned short*)(ws + 16384); // 12288 ushorts (24KB)
    uint2* xb           = (uint2*)(ws + 32768);          // NPTS uint2 (10.5MB)

    float* yr = (float*)d_out;
    float* yi = yr + (size_t)NPTS * F_;

    hipLaunchKernelGGL(project_kernel, dim3(64), dim3(64), 0, stream,
                       wxr, wxi, wtr, wti, psr, psi, ptr_, pti);
    hipLaunchKernelGGL(pack_kernel, dim3(40), dim3(256), 0, stream,
                       psr, psi, ptr_, pti, wsp, wp);
    hipLaunchKernelGGL(repack_kernel, dim3(NPTS/256), dim3(256), 0, stream,
                       xr, xi, xb);
    hipLaunchKernelGGL(fused_kernel, dim3(B_*Z_*Y_), dim3(256), 0, stream,
                       xb, wsp, wp, yr, yi);
}